// Round 7
// baseline (1225.000 us; speedup 1.0000x reference)
//
#include <hip/hip_runtime.h>
#include <hip/hip_bf16.h>
#include <cstddef>

#define B 64
#define S 128
#define H 1024
#define V 32000
#define T 10
#define H3 3072
#define NCHUNK 250

typedef __bf16 bf16x8 __attribute__((ext_vector_type(8)));
typedef float f32x4 __attribute__((ext_vector_type(4)));
typedef unsigned short ushort8v __attribute__((ext_vector_type(8)));

__device__ inline unsigned short f2b(float f) {
    __hip_bfloat16 h = __float2bfloat16(f);
    return *reinterpret_cast<unsigned short*>(&h);
}
__device__ inline float b2f(unsigned short u) {
    return __uint_as_float(((unsigned)u) << 16);
}
__device__ inline float fast_tanh(float x) {
    float e = __expf(2.f * x);
    return 1.f - 2.f * __builtin_amdgcn_rcpf(e + 1.f);
}
__device__ inline float fast_sigmoid(float x) {
    return __builtin_amdgcn_rcpf(1.f + __expf(-x));
}

// bijective XCD swizzle (m204)
__device__ inline int xcd_swz(int orig, int nwg) {
    int q = nwg >> 3, r = nwg & 7;
    int xcd = orig & 7, idx = orig >> 3;
    int base = (xcd < r) ? xcd * (q + 1) : r * (q + 1) + (xcd - r) * q;
    return base + idx;
}

// ---------------- unified prep kernel (all conversions/builds in ONE launch) ----------------
// block ranges: [0,8192) enc | [8192,40192) out_w | [40192,41216) Ua
// [41216,45312) Wcat | [45312,48384) Wemb | [48384,51456) Wctx
// [51456,51472) catbias | [51472,52112) embg
__global__ void prep_kernel(const float* __restrict__ enc, unsigned short* __restrict__ enc_bf,
                            const float* __restrict__ out_w, unsigned short* __restrict__ outw_bf,
                            const float* __restrict__ Ua_w, unsigned short* __restrict__ Ua_bf,
                            const float* __restrict__ gwh, const float* __restrict__ Wa_w,
                            unsigned short* __restrict__ Wcat,
                            const float* __restrict__ gwi,
                            unsigned short* __restrict__ Wemb, unsigned short* __restrict__ Wctx,
                            const float* __restrict__ gbh, const float* __restrict__ Wa_b,
                            float* __restrict__ catbias,
                            const float* __restrict__ emb, const int* __restrict__ tgt,
                            unsigned short* __restrict__ embg) {
    const int bid = blockIdx.x, tid = threadIdx.x;
    if (bid < 8192) {                   // enc fp32 -> bf16
        int i = bid * 256 + tid;
        float4 v = reinterpret_cast<const float4*>(enc)[i];
        ushort4 o = { f2b(v.x), f2b(v.y), f2b(v.z), f2b(v.w) };
        reinterpret_cast<ushort4*>(enc_bf)[i] = o;
    } else if (bid < 40192) {           // out_w -> bf16
        int i = (bid - 8192) * 256 + tid;
        float4 v = reinterpret_cast<const float4*>(out_w)[i];
        ushort4 o = { f2b(v.x), f2b(v.y), f2b(v.z), f2b(v.w) };
        reinterpret_cast<ushort4*>(outw_bf)[i] = o;
    } else if (bid < 41216) {           // Ua_w -> bf16
        int i = (bid - 40192) * 256 + tid;
        float4 v = reinterpret_cast<const float4*>(Ua_w)[i];
        ushort4 o = { f2b(v.x), f2b(v.y), f2b(v.z), f2b(v.w) };
        reinterpret_cast<ushort4*>(Ua_bf)[i] = o;
    } else if (bid < 45312) {           // Wcat = [gwh ; Wa_w]
        int i = (bid - 41216) * 256 + tid;
        int e = i * 4, n = e >> 10, k = e & 1023;
        const float* src = (n < H3) ? (gwh + (size_t)n * H + k) : (Wa_w + (size_t)(n - H3) * H + k);
        float4 v = *reinterpret_cast<const float4*>(src);
        ushort4 o = { f2b(v.x), f2b(v.y), f2b(v.z), f2b(v.w) };
        reinterpret_cast<ushort4*>(Wcat)[i] = o;
    } else if (bid < 48384) {           // Wemb = gwi[:, 0:H]
        int i = (bid - 45312) * 256 + tid;
        int e = i * 4, n = e >> 10, k = e & 1023;
        float4 v = *reinterpret_cast<const float4*>(gwi + (size_t)n * 2 * H + k);
        ushort4 o = { f2b(v.x), f2b(v.y), f2b(v.z), f2b(v.w) };
        reinterpret_cast<ushort4*>(Wemb)[i] = o;
    } else if (bid < 51456) {           // Wctx = gwi[:, H:2H]
        int i = (bid - 48384) * 256 + tid;
        int e = i * 4, n = e >> 10, k = e & 1023;
        float4 v = *reinterpret_cast<const float4*>(gwi + (size_t)n * 2 * H + H + k);
        ushort4 o = { f2b(v.x), f2b(v.y), f2b(v.z), f2b(v.w) };
        reinterpret_cast<ushort4*>(Wctx)[i] = o;
    } else if (bid < 51472) {           // catbias
        int n = (bid - 51456) * 256 + tid;
        catbias[n] = (n < H3) ? gbh[n] : Wa_b[n - H3];
    } else {                            // embg gather (bf16)
        int i = (bid - 51472) * 256 + tid;
        int e = i * 4;
        int t = e >> 16, rem = e & 65535;
        int b = rem >> 10, j = rem & 1023;
        int tok = (t == 0) ? 0 : tgt[b * T + (t - 1)];
        float4 v = *reinterpret_cast<const float4*>(emb + (size_t)tok * H + j);
        ushort4 o = { f2b(v.x), f2b(v.y), f2b(v.z), f2b(v.w) };
        *reinterpret_cast<ushort4*>(embg + ((size_t)t * B + b) * H + j) = o;
    }
}

// ---------------- big MFMA GEMM: 128x128 tile, BK=64, 512 thr, 1D grid + XCD swizzle ----------------
template <int OUT_BF16, int STATS>
__global__ __launch_bounds__(512) void gemm_big(const unsigned short* __restrict__ A,
                                                const unsigned short* __restrict__ Bw,
                                                const float* __restrict__ bias,
                                                void* __restrict__ Cout,
                                                float2* __restrict__ stats,
                                                int M, int N, int K) {
    __shared__ unsigned short As[128][72];
    __shared__ unsigned short Bs[128][72];
    __shared__ float mred[128][4];
    __shared__ float sred[128][4];
    const int wg = xcd_swz(blockIdx.x, gridDim.x);
    const int mtiles = M >> 7;
    const int bm = (wg % mtiles) << 7, bn = (wg / mtiles) << 7;
    const int tid = threadIdx.x, lane = tid & 63, w = tid >> 6;
    const int wm = w >> 2, wn = w & 3;
    const int quad = lane >> 4, fr = lane & 15;
    f32x4 acc[4][2] = {};

    const int srow = tid >> 2, sc16 = (tid & 3) * 16;
    for (int k0 = 0; k0 < K; k0 += 64) {
        const unsigned short* ap = A + (size_t)(bm + srow) * K + k0 + sc16;
        *reinterpret_cast<bf16x8*>(&As[srow][sc16])     = *reinterpret_cast<const bf16x8*>(ap);
        *reinterpret_cast<bf16x8*>(&As[srow][sc16 + 8]) = *reinterpret_cast<const bf16x8*>(ap + 8);
        const unsigned short* bp = Bw + (size_t)(bn + srow) * K + k0 + sc16;
        *reinterpret_cast<bf16x8*>(&Bs[srow][sc16])     = *reinterpret_cast<const bf16x8*>(bp);
        *reinterpret_cast<bf16x8*>(&Bs[srow][sc16 + 8]) = *reinterpret_cast<const bf16x8*>(bp + 8);
        __syncthreads();
        #pragma unroll
        for (int ks = 0; ks < 2; ++ks) {
            const int kg = quad * 8 + 32 * ks;
            bf16x8 a[4], bb[2];
            #pragma unroll
            for (int m = 0; m < 4; ++m)
                a[m] = *reinterpret_cast<const bf16x8*>(&As[64 * wm + 16 * m + fr][kg]);
            #pragma unroll
            for (int n = 0; n < 2; ++n)
                bb[n] = *reinterpret_cast<const bf16x8*>(&Bs[32 * wn + 16 * n + fr][kg]);
            #pragma unroll
            for (int m = 0; m < 4; ++m)
                #pragma unroll
                for (int n = 0; n < 2; ++n)
                    acc[m][n] = __builtin_amdgcn_mfma_f32_16x16x32_bf16(a[m], bb[n], acc[m][n], 0, 0, 0);
        }
        __syncthreads();
    }

    #pragma unroll
    for (int n = 0; n < 2; ++n) {
        int col = bn + 32 * wn + 16 * n + fr;
        float bv = bias ? bias[col] : 0.f;
        #pragma unroll
        for (int m = 0; m < 4; ++m)
            #pragma unroll
            for (int i = 0; i < 4; ++i) {
                int row = bm + 64 * wm + 16 * m + quad * 4 + i;
                float v = acc[m][n][i] + bv;
                if (OUT_BF16)
                    ((unsigned short*)Cout)[(size_t)row * N + col] = f2b(v);
                else
                    ((float*)Cout)[(size_t)row * N + col] = v;
                if (STATS) acc[m][n][i] = v;
            }
    }

    if (STATS) {
        const int nchunk = N >> 7;
        #pragma unroll
        for (int m = 0; m < 4; ++m)
            #pragma unroll
            for (int i = 0; i < 4; ++i) {
                float x = fmaxf(acc[m][0][i], acc[m][1][i]);
                x = fmaxf(x, __shfl_xor(x, 1)); x = fmaxf(x, __shfl_xor(x, 2));
                x = fmaxf(x, __shfl_xor(x, 4)); x = fmaxf(x, __shfl_xor(x, 8));
                if (fr == 0) mred[64 * wm + 16 * m + quad * 4 + i][wn] = x;
            }
        __syncthreads();
        #pragma unroll
        for (int m = 0; m < 4; ++m)
            #pragma unroll
            for (int i = 0; i < 4; ++i) {
                int rl = 64 * wm + 16 * m + quad * 4 + i;
                float Mr = fmaxf(fmaxf(mred[rl][0], mred[rl][1]), fmaxf(mred[rl][2], mred[rl][3]));
                float sv = expf(acc[m][0][i] - Mr) + expf(acc[m][1][i] - Mr);
                sv += __shfl_xor(sv, 1); sv += __shfl_xor(sv, 2);
                sv += __shfl_xor(sv, 4); sv += __shfl_xor(sv, 8);
                if (fr == 0) sred[rl][wn] = sv;
            }
        __syncthreads();
        if (tid < 128) {
            float Mr = fmaxf(fmaxf(mred[tid][0], mred[tid][1]), fmaxf(mred[tid][2], mred[tid][3]));
            float Sv = sred[tid][0] + sred[tid][1] + sred[tid][2] + sred[tid][3];
            stats[(size_t)(bm + tid) * nchunk + (bn >> 7)] = make_float2(Mr, Sv);
        }
    }
}

// ---------------- device-scope barrier for 64 co-resident blocks ----------------
__device__ inline void dev_barrier64(unsigned int* ctr) {
    __syncthreads();
    if (threadIdx.x == 0) {
        __threadfence();                                   // agent release (L2 wb)
        atomicAdd(ctr, 1u);
        while (__hip_atomic_load(ctr, __ATOMIC_RELAXED, __HIP_MEMORY_SCOPE_AGENT) < 64u)
            __builtin_amdgcn_s_sleep(1);
        __builtin_amdgcn_fence(__ATOMIC_ACQUIRE, "agent"); // invalidate stale caches
    }
    __syncthreads();
}

// ---------------- persistent kernel: ALL T steps in one launch ----------------
// grid(64) x 256 thr. Phase A: block n -> ghq[:, n*64:+64]. Phase B: block b = batch b.
// h state lives in registers (thread owns h[b, tid*4 .. +4)).
__global__ __launch_bounds__(256) void steps_kernel(const float* __restrict__ h0,
                                                    unsigned short* __restrict__ hbf,
                                                    const unsigned short* __restrict__ Wcat,
                                                    const float* __restrict__ catbias,
                                                    float* __restrict__ ghq,
                                                    const unsigned short* __restrict__ keys,
                                                    const unsigned short* __restrict__ KV,
                                                    const float* __restrict__ va,
                                                    const float* __restrict__ va_b,
                                                    const float* __restrict__ gi_emb,
                                                    unsigned short* __restrict__ outs_bf,
                                                    float* __restrict__ attns,
                                                    float* __restrict__ h_final,
                                                    unsigned int* __restrict__ ctrs) {
    __shared__ unsigned short As[64][72];
    __shared__ unsigned short Bs[64][72];
    __shared__ float ssc[128];
    __shared__ float sw[128];
    const int bid = blockIdx.x;
    const int tid = threadIdx.x, lane = tid & 63, wv = tid >> 6;
    const int quad = lane >> 4, fr = lane & 15;
    const int j0 = tid * 4;
    int barrier_idx = 0;

    // persistent per-thread h state (fp32) + va cache
    float hv[4];
    *reinterpret_cast<float4*>(hv) = *reinterpret_cast<const float4*>(h0 + (size_t)bid * H + j0);
    float vv[16];
    {
        const float* vp = va + lane * 16;
        #pragma unroll
        for (int j = 0; j < 16; ++j) vv[j] = vp[j];
    }
    const float vab = va_b[0];
    // init hbf[bid,:]
    {
        ushort4 hb;
        unsigned short* hbp = reinterpret_cast<unsigned short*>(&hb);
        #pragma unroll
        for (int i = 0; i < 4; ++i) hbp[i] = f2b(hv[i]);
        *reinterpret_cast<ushort4*>(hbf + (size_t)bid * H + j0) = hb;
    }
    dev_barrier64(&ctrs[barrier_idx++]);

    for (int t = 0; t < T; ++t) {
        // ===== phase A: ghq[:, bn:bn+64] = hbf @ Wcat[bn:bn+64,:]^T + catbias =====
        {
            const int bn = bid << 6;
            f32x4 acc0[4] = {}, acc1[4] = {}, acc2[4] = {}, acc3[4] = {};
            f32x4* accs[4] = { acc0, acc1, acc2, acc3 };
            const int srow = tid >> 2, sc16 = (tid & 3) * 16;
            for (int k0 = 0; k0 < H; k0 += 64) {
                const unsigned short* ap = hbf + (size_t)srow * H + k0 + sc16;
                *reinterpret_cast<bf16x8*>(&As[srow][sc16])     = *reinterpret_cast<const bf16x8*>(ap);
                *reinterpret_cast<bf16x8*>(&As[srow][sc16 + 8]) = *reinterpret_cast<const bf16x8*>(ap + 8);
                const unsigned short* bp = Wcat + (size_t)(bn + srow) * H + k0 + sc16;
                *reinterpret_cast<bf16x8*>(&Bs[srow][sc16])     = *reinterpret_cast<const bf16x8*>(bp);
                *reinterpret_cast<bf16x8*>(&Bs[srow][sc16 + 8]) = *reinterpret_cast<const bf16x8*>(bp + 8);
                __syncthreads();
                #pragma unroll
                for (int ks = 0; ks < 2; ++ks) {
                    const int kg = quad * 8 + 32 * ks;
                    bf16x8 bb = *reinterpret_cast<const bf16x8*>(&Bs[16 * wv + fr][kg]);
                    #pragma unroll
                    for (int m = 0; m < 4; ++m) {
                        bf16x8 a = *reinterpret_cast<const bf16x8*>(&As[16 * m + fr][kg]);
                        accs[m][0] = __builtin_amdgcn_mfma_f32_16x16x32_bf16(a, bb, accs[m][0], 0, 0, 0);
                    }
                }
                __syncthreads();
            }
            int col = bn + 16 * wv + fr;
            float bv = catbias[col];
            #pragma unroll
            for (int m = 0; m < 4; ++m)
                #pragma unroll
                for (int i = 0; i < 4; ++i) {
                    int row = 16 * m + quad * 4 + i;
                    ghq[(size_t)row * 4096 + col] = accs[m][0][i] + bv;
                }
        }
        dev_barrier64(&ctrs[barrier_idx++]);

        // ===== phase B: fused attention + GRU for batch b =====
        const int b = bid;
        float qv[16];
        {
            const float* qp = ghq + (size_t)b * 4096 + H3 + lane * 16;
            #pragma unroll
            for (int j = 0; j < 16; ++j) qv[j] = qp[j];
        }
        const unsigned short* kb = keys + (size_t)b * S * H;
        for (int i = 0; i < 32; ++i) {
            int s = wv * 32 + i;
            const unsigned short* kr = kb + (size_t)s * H + lane * 16;
            ushort8v k0 = *reinterpret_cast<const ushort8v*>(kr);
            ushort8v k1 = *reinterpret_cast<const ushort8v*>(kr + 8);
            float acc = 0.f;
            #pragma unroll
            for (int e = 0; e < 8; ++e) acc += fast_tanh(qv[e] + b2f(k0[e])) * vv[e];
            #pragma unroll
            for (int e = 0; e < 8; ++e) acc += fast_tanh(qv[8 + e] + b2f(k1[e])) * vv[8 + e];
            acc += __shfl_xor(acc, 1);  acc += __shfl_xor(acc, 2);
            acc += __shfl_xor(acc, 4);  acc += __shfl_xor(acc, 8);
            acc += __shfl_xor(acc, 16); acc += __shfl_xor(acc, 32);
            if (lane == 0) ssc[s] = acc + vab;
        }
        __syncthreads();
        if (tid < 128) {
            float mx = -1e30f;
            #pragma unroll 8
            for (int s = 0; s < 128; ++s) mx = fmaxf(mx, ssc[s]);
            float sum = 0.f;
            #pragma unroll 8
            for (int s = 0; s < 128; ++s) sum += __expf(ssc[s] - mx);
            float wvv = __expf(ssc[tid] - mx) / sum;
            sw[tid] = wvv;
            attns[((size_t)b * T + t) * S + tid] = wvv;
        }
        __syncthreads();

        float accr[4] = {}, accz[4] = {}, accn[4] = {};
        const unsigned short* kvb = KV + (size_t)b * S * H3;
        #pragma unroll 4
        for (int s = 0; s < S; ++s) {
            float ws = sw[s];
            const unsigned short* row = kvb + (size_t)s * H3;
            uint2 u0 = *reinterpret_cast<const uint2*>(row + j0);
            uint2 u1 = *reinterpret_cast<const uint2*>(row + 1024 + j0);
            uint2 u2 = *reinterpret_cast<const uint2*>(row + 2048 + j0);
            accr[0] += ws * b2f((unsigned short)(u0.x & 0xffff));
            accr[1] += ws * b2f((unsigned short)(u0.x >> 16));
            accr[2] += ws * b2f((unsigned short)(u0.y & 0xffff));
            accr[3] += ws * b2f((unsigned short)(u0.y >> 16));
            accz[0] += ws * b2f((unsigned short)(u1.x & 0xffff));
            accz[1] += ws * b2f((unsigned short)(u1.x >> 16));
            accz[2] += ws * b2f((unsigned short)(u1.y & 0xffff));
            accz[3] += ws * b2f((unsigned short)(u1.y >> 16));
            accn[0] += ws * b2f((unsigned short)(u2.x & 0xffff));
            accn[1] += ws * b2f((unsigned short)(u2.x >> 16));
            accn[2] += ws * b2f((unsigned short)(u2.y & 0xffff));
            accn[3] += ws * b2f((unsigned short)(u2.y >> 16));
        }
        const float* ge = gi_emb + ((size_t)t * B + b) * H3;
        const float* gh = ghq + (size_t)b * 4096;
        float geR[4], geZ[4], geN[4], ghR[4], ghZ[4], ghN[4];
        *reinterpret_cast<float4*>(geR) = *reinterpret_cast<const float4*>(ge + j0);
        *reinterpret_cast<float4*>(geZ) = *reinterpret_cast<const float4*>(ge + 1024 + j0);
        *reinterpret_cast<float4*>(geN) = *reinterpret_cast<const float4*>(ge + 2048 + j0);
        *reinterpret_cast<float4*>(ghR) = *reinterpret_cast<const float4*>(gh + j0);
        *reinterpret_cast<float4*>(ghZ) = *reinterpret_cast<const float4*>(gh + 1024 + j0);
        *reinterpret_cast<float4*>(ghN) = *reinterpret_cast<const float4*>(gh + 2048 + j0);
        ushort4 hb;
        unsigned short* hbp = reinterpret_cast<unsigned short*>(&hb);
        #pragma unroll
        for (int i = 0; i < 4; ++i) {
            float r = fast_sigmoid(geR[i] + accr[i] + ghR[i]);
            float z = fast_sigmoid(geZ[i] + accz[i] + ghZ[i]);
            float n = fast_tanh(geN[i] + accn[i] + r * ghN[i]);
            hv[i] = (1.f - z) * n + z * hv[i];
            hbp[i] = f2b(hv[i]);
        }
        *reinterpret_cast<ushort4*>(hbf + (size_t)b * H + j0) = hb;
        *reinterpret_cast<ushort4*>(outs_bf + ((size_t)b * T + t) * H + j0) = hb;
        if (t == T - 1)
            *reinterpret_cast<float4*>(h_final + (size_t)b * H + j0) = *reinterpret_cast<float4*>(hv);
        dev_barrier64(&ctrs[barrier_idx++]);
    }
}

// ---------------- log-softmax finalize ----------------
__global__ void lse_kernel(const float2* __restrict__ stats, float* __restrict__ lse) {
    const int row = blockIdx.x;
    const int tid = threadIdx.x;   // 256
    __shared__ float shm[256];
    __shared__ float shs[256];
    float mv = -1e30f, sv = 0.f;
    float2 st = make_float2(-1e30f, 0.f);
    if (tid < NCHUNK) { st = stats[(size_t)row * NCHUNK + tid]; mv = st.x; }
    shm[tid] = mv; __syncthreads();
    for (int off = 128; off > 0; off >>= 1) {
        if (tid < off) shm[tid] = fmaxf(shm[tid], shm[tid + off]);
        __syncthreads();
    }
    float M = shm[0]; __syncthreads();
    if (tid < NCHUNK) sv = st.y * expf(st.x - M);
    shs[tid] = sv; __syncthreads();
    for (int off = 128; off > 0; off >>= 1) {
        if (tid < off) shs[tid] += shs[tid + off];
        __syncthreads();
    }
    if (tid == 0) lse[row] = M + logf(shs[0]);
}

__global__ void sub_lse(float* __restrict__ x, const float* __restrict__ lse) {
    const int n4 = B * T * (V / 4);
    float4* p = reinterpret_cast<float4*>(x);
    for (int i = blockIdx.x * 256 + threadIdx.x; i < n4; i += gridDim.x * 256) {
        int row = i / (V / 4);
        float l = lse[row];
        float4 v = p[i];
        v.x -= l; v.y -= l; v.z -= l; v.w -= l;
        p[i] = v;
    }
}

// ---------------- host ----------------

extern "C" void kernel_launch(void* const* d_in, const int* in_sizes, int n_in,
                              void* d_out, int out_size, void* d_ws, size_t ws_size,
                              hipStream_t stream) {
    const float* enc   = (const float*)d_in[0];
    const float* h0    = (const float*)d_in[1];
    const int*   tgt   = (const int*)d_in[2];
    const float* emb   = (const float*)d_in[3];
    const float* Wa_w  = (const float*)d_in[4];
    const float* Wa_b  = (const float*)d_in[5];
    const float* Ua_w  = (const float*)d_in[6];
    const float* Ua_b  = (const float*)d_in[7];
    const float* Va_w  = (const float*)d_in[8];
    const float* Va_b  = (const float*)d_in[9];
    const float* gwi   = (const float*)d_in[10];
    const float* gwh   = (const float*)d_in[11];
    const float* gbi   = (const float*)d_in[12];
    const float* gbh   = (const float*)d_in[13];
    const float* out_w = (const float*)d_in[14];
    const float* out_b = (const float*)d_in[15];

    float* out       = (float*)d_out;
    float* log_probs = out;                          // [B*T, V]
    float* h_final   = out + (size_t)B * T * V;      // [B, H]
    float* attns     = h_final + (size_t)B * H;      // [B, T, S]

    char* pp = (char*)d_ws;
    auto alloc = [&](size_t bytes) { char* r = pp; pp += (bytes + 255) & ~(size_t)255; return r; };
    unsigned short* ua_bf   = (unsigned short*)alloc((size_t)B * S * H * 2);
    unsigned short* enc_bf  = (unsigned short*)alloc((size_t)B * S * H * 2);
    unsigned short* outw_bf = (unsigned short*)alloc((size_t)V * H * 2);
    unsigned short* KV      = (unsigned short*)alloc((size_t)B * S * H3 * 2);
    unsigned short* Ua_bf   = (unsigned short*)alloc((size_t)H * H * 2);
    unsigned short* Wcat    = (unsigned short*)alloc((size_t)4096 * H * 2);
    unsigned short* Wctx    = (unsigned short*)alloc((size_t)H3 * H * 2);
    unsigned short* Wemb    = (unsigned short*)alloc((size_t)H3 * H * 2);
    float*          catbias = (float*)alloc(4096 * 4);
    unsigned short* embg    = (unsigned short*)alloc((size_t)T * B * H * 2);
    float*          gi_emb  = (float*)alloc((size_t)T * B * H3 * 4);
    unsigned short* hbf     = (unsigned short*)alloc((size_t)B * H * 2);
    float*          ghq     = (float*)alloc((size_t)B * 4096 * 4);
    unsigned short* outs_bf = (unsigned short*)alloc((size_t)B * T * H * 2);
    float2*         stats   = (float2*)alloc((size_t)B * T * NCHUNK * 8);
    float*          lse     = (float*)alloc((size_t)B * T * 4);
    unsigned int*   ctrs    = (unsigned int*)alloc(64 * 4);

    hipMemsetAsync(ctrs, 0, 64 * sizeof(unsigned int), stream);

    // all conversions/builds in one launch
    prep_kernel<<<52112, 256, 0, stream>>>(enc, enc_bf, out_w, outw_bf, Ua_w, Ua_bf,
                                           gwh, Wa_w, Wcat, gwi, Wemb, Wctx,
                                           gbh, Wa_b, catbias, emb, tgt, embg);

    // ua_keys = enc @ Ua_w^T + Ua_b -> bf16 [B*S, H]
    gemm_big<1, 0><<<(B * S / 128) * (H / 128), 512, 0, stream>>>(
        enc_bf, Ua_bf, Ua_b, ua_bf, nullptr, B * S, H, H);
    // KV = enc @ Wctx^T -> bf16 [B*S, 3072]
    gemm_big<1, 0><<<(B * S / 128) * (H3 / 128), 512, 0, stream>>>(
        enc_bf, Wctx, nullptr, KV, nullptr, B * S, H3, H);
    // gi_emb = embg @ Wemb^T + gbi -> fp32 [T*B, 3072]
    gemm_big<0, 0><<<(T * B / 128) * (H3 / 128), 512, 0, stream>>>(
        embg, Wemb, gbi, gi_emb, nullptr, T * B, H3, H);

    // ALL recurrent steps in one persistent launch
    steps_kernel<<<B, 256, 0, stream>>>(h0, hbf, Wcat, catbias, ghq, ua_bf, KV,
                                        Va_w, Va_b, gi_emb, outs_bf, attns, h_final, ctrs);

    // logits = outs @ out_w^T + out_b  [640, 32000] + fused softmax stats
    gemm_big<0, 1><<<(B * T / 128) * (V / 128), 512, 0, stream>>>(
        outs_bf, outw_bf, out_b, log_probs, stats, B * T, V, H);
    lse_kernel<<<B * T, 256, 0, stream>>>(stats, lse);
    sub_lse<<<2048, 256, 0, stream>>>(log_probs, lse);
}

// Round 8
// 902.841 us; speedup vs baseline: 1.3568x; 1.3568x over previous
//
#include <hip/hip_runtime.h>
#include <hip/hip_bf16.h>
#include <cstddef>

#define B 64
#define S 128
#define H 1024
#define V 32000
#define T 10
#define H3 3072
#define NCHUNK 250

typedef __bf16 bf16x8 __attribute__((ext_vector_type(8)));
typedef float f32x4 __attribute__((ext_vector_type(4)));
typedef unsigned short ushort8v __attribute__((ext_vector_type(8)));

__device__ inline unsigned short f2b(float f) {
    __hip_bfloat16 h = __float2bfloat16(f);
    return *reinterpret_cast<unsigned short*>(&h);
}
__device__ inline float b2f(unsigned short u) {
    return __uint_as_float(((unsigned)u) << 16);
}
__device__ inline float fast_tanh(float x) {
    float e = __expf(2.f * x);
    return 1.f - 2.f * __builtin_amdgcn_rcpf(e + 1.f);
}
__device__ inline float fast_sigmoid(float x) {
    return __builtin_amdgcn_rcpf(1.f + __expf(-x));
}

// bijective XCD swizzle (m204)
__device__ inline int xcd_swz(int orig, int nwg) {
    int q = nwg >> 3, r = nwg & 7;
    int xcd = orig & 7, idx = orig >> 3;
    int base = (xcd < r) ? xcd * (q + 1) : r * (q + 1) + (xcd - r) * q;
    return base + idx;
}

// ---------------- unified prep kernel (all conversions/builds in ONE launch) ----------------
// block ranges: [0,8192) enc | [8192,40192) out_w | [40192,41216) Ua
// [41216,45312) Wcat | [45312,48384) Wemb | [48384,51456) Wctx
// [51456,51472) catbias | [51472,52112) embg | [52112,52176) hbf
__global__ void prep_kernel(const float* __restrict__ enc, unsigned short* __restrict__ enc_bf,
                            const float* __restrict__ out_w, unsigned short* __restrict__ outw_bf,
                            const float* __restrict__ Ua_w, unsigned short* __restrict__ Ua_bf,
                            const float* __restrict__ gwh, const float* __restrict__ Wa_w,
                            unsigned short* __restrict__ Wcat,
                            const float* __restrict__ gwi,
                            unsigned short* __restrict__ Wemb, unsigned short* __restrict__ Wctx,
                            const float* __restrict__ gbh, const float* __restrict__ Wa_b,
                            float* __restrict__ catbias,
                            const float* __restrict__ emb, const int* __restrict__ tgt,
                            unsigned short* __restrict__ embg,
                            const float* __restrict__ h0, unsigned short* __restrict__ hbf) {
    const int bid = blockIdx.x, tid = threadIdx.x;
    if (bid < 8192) {                   // enc fp32 -> bf16
        int i = bid * 256 + tid;
        float4 v = reinterpret_cast<const float4*>(enc)[i];
        ushort4 o = { f2b(v.x), f2b(v.y), f2b(v.z), f2b(v.w) };
        reinterpret_cast<ushort4*>(enc_bf)[i] = o;
    } else if (bid < 40192) {           // out_w -> bf16
        int i = (bid - 8192) * 256 + tid;
        float4 v = reinterpret_cast<const float4*>(out_w)[i];
        ushort4 o = { f2b(v.x), f2b(v.y), f2b(v.z), f2b(v.w) };
        reinterpret_cast<ushort4*>(outw_bf)[i] = o;
    } else if (bid < 41216) {           // Ua_w -> bf16
        int i = (bid - 40192) * 256 + tid;
        float4 v = reinterpret_cast<const float4*>(Ua_w)[i];
        ushort4 o = { f2b(v.x), f2b(v.y), f2b(v.z), f2b(v.w) };
        reinterpret_cast<ushort4*>(Ua_bf)[i] = o;
    } else if (bid < 45312) {           // Wcat = [gwh ; Wa_w]
        int i = (bid - 41216) * 256 + tid;
        int e = i * 4, n = e >> 10, k = e & 1023;
        const float* src = (n < H3) ? (gwh + (size_t)n * H + k) : (Wa_w + (size_t)(n - H3) * H + k);
        float4 v = *reinterpret_cast<const float4*>(src);
        ushort4 o = { f2b(v.x), f2b(v.y), f2b(v.z), f2b(v.w) };
        reinterpret_cast<ushort4*>(Wcat)[i] = o;
    } else if (bid < 48384) {           // Wemb = gwi[:, 0:H]
        int i = (bid - 45312) * 256 + tid;
        int e = i * 4, n = e >> 10, k = e & 1023;
        float4 v = *reinterpret_cast<const float4*>(gwi + (size_t)n * 2 * H + k);
        ushort4 o = { f2b(v.x), f2b(v.y), f2b(v.z), f2b(v.w) };
        reinterpret_cast<ushort4*>(Wemb)[i] = o;
    } else if (bid < 51456) {           // Wctx = gwi[:, H:2H]
        int i = (bid - 48384) * 256 + tid;
        int e = i * 4, n = e >> 10, k = e & 1023;
        float4 v = *reinterpret_cast<const float4*>(gwi + (size_t)n * 2 * H + H + k);
        ushort4 o = { f2b(v.x), f2b(v.y), f2b(v.z), f2b(v.w) };
        reinterpret_cast<ushort4*>(Wctx)[i] = o;
    } else if (bid < 51472) {           // catbias
        int n = (bid - 51456) * 256 + tid;
        catbias[n] = (n < H3) ? gbh[n] : Wa_b[n - H3];
    } else if (bid < 52112) {           // embg gather (bf16)
        int i = (bid - 51472) * 256 + tid;
        int e = i * 4;
        int t = e >> 16, rem = e & 65535;
        int b = rem >> 10, j = rem & 1023;
        int tok = (t == 0) ? 0 : tgt[b * T + (t - 1)];
        float4 v = *reinterpret_cast<const float4*>(emb + (size_t)tok * H + j);
        ushort4 o = { f2b(v.x), f2b(v.y), f2b(v.z), f2b(v.w) };
        *reinterpret_cast<ushort4*>(embg + ((size_t)t * B + b) * H + j) = o;
    } else {                            // hbf = bf16(h0)
        int i = (bid - 52112) * 256 + tid;
        float4 v = reinterpret_cast<const float4*>(h0)[i];
        ushort4 o = { f2b(v.x), f2b(v.y), f2b(v.z), f2b(v.w) };
        reinterpret_cast<ushort4*>(hbf)[i] = o;
    }
}

// ---------------- big MFMA GEMM: 128x128 tile, BK=64, 512 thr, 1D grid + XCD swizzle ----------------
template <int OUT_BF16, int STATS>
__global__ __launch_bounds__(512) void gemm_big(const unsigned short* __restrict__ A,
                                                const unsigned short* __restrict__ Bw,
                                                const float* __restrict__ bias,
                                                void* __restrict__ Cout,
                                                float2* __restrict__ stats,
                                                int M, int N, int K) {
    __shared__ unsigned short As[128][72];
    __shared__ unsigned short Bs[128][72];
    __shared__ float mred[128][4];
    __shared__ float sred[128][4];
    const int wg = xcd_swz(blockIdx.x, gridDim.x);
    const int mtiles = M >> 7;
    const int bm = (wg % mtiles) << 7, bn = (wg / mtiles) << 7;
    const int tid = threadIdx.x, lane = tid & 63, w = tid >> 6;
    const int wm = w >> 2, wn = w & 3;
    const int quad = lane >> 4, fr = lane & 15;
    f32x4 acc[4][2] = {};

    const int srow = tid >> 2, sc16 = (tid & 3) * 16;
    for (int k0 = 0; k0 < K; k0 += 64) {
        const unsigned short* ap = A + (size_t)(bm + srow) * K + k0 + sc16;
        *reinterpret_cast<bf16x8*>(&As[srow][sc16])     = *reinterpret_cast<const bf16x8*>(ap);
        *reinterpret_cast<bf16x8*>(&As[srow][sc16 + 8]) = *reinterpret_cast<const bf16x8*>(ap + 8);
        const unsigned short* bp = Bw + (size_t)(bn + srow) * K + k0 + sc16;
        *reinterpret_cast<bf16x8*>(&Bs[srow][sc16])     = *reinterpret_cast<const bf16x8*>(bp);
        *reinterpret_cast<bf16x8*>(&Bs[srow][sc16 + 8]) = *reinterpret_cast<const bf16x8*>(bp + 8);
        __syncthreads();
        #pragma unroll
        for (int ks = 0; ks < 2; ++ks) {
            const int kg = quad * 8 + 32 * ks;
            bf16x8 a[4], bb[2];
            #pragma unroll
            for (int m = 0; m < 4; ++m)
                a[m] = *reinterpret_cast<const bf16x8*>(&As[64 * wm + 16 * m + fr][kg]);
            #pragma unroll
            for (int n = 0; n < 2; ++n)
                bb[n] = *reinterpret_cast<const bf16x8*>(&Bs[32 * wn + 16 * n + fr][kg]);
            #pragma unroll
            for (int m = 0; m < 4; ++m)
                #pragma unroll
                for (int n = 0; n < 2; ++n)
                    acc[m][n] = __builtin_amdgcn_mfma_f32_16x16x32_bf16(a[m], bb[n], acc[m][n], 0, 0, 0);
        }
        __syncthreads();
    }

    #pragma unroll
    for (int n = 0; n < 2; ++n) {
        int col = bn + 32 * wn + 16 * n + fr;
        float bv = bias ? bias[col] : 0.f;
        #pragma unroll
        for (int m = 0; m < 4; ++m)
            #pragma unroll
            for (int i = 0; i < 4; ++i) {
                int row = bm + 64 * wm + 16 * m + quad * 4 + i;
                float v = acc[m][n][i] + bv;
                if (OUT_BF16)
                    ((unsigned short*)Cout)[(size_t)row * N + col] = f2b(v);
                else
                    ((float*)Cout)[(size_t)row * N + col] = v;
                if (STATS) acc[m][n][i] = v;
            }
    }

    if (STATS) {
        const int nchunk = N >> 7;
        #pragma unroll
        for (int m = 0; m < 4; ++m)
            #pragma unroll
            for (int i = 0; i < 4; ++i) {
                float x = fmaxf(acc[m][0][i], acc[m][1][i]);
                x = fmaxf(x, __shfl_xor(x, 1)); x = fmaxf(x, __shfl_xor(x, 2));
                x = fmaxf(x, __shfl_xor(x, 4)); x = fmaxf(x, __shfl_xor(x, 8));
                if (fr == 0) mred[64 * wm + 16 * m + quad * 4 + i][wn] = x;
            }
        __syncthreads();
        #pragma unroll
        for (int m = 0; m < 4; ++m)
            #pragma unroll
            for (int i = 0; i < 4; ++i) {
                int rl = 64 * wm + 16 * m + quad * 4 + i;
                float Mr = fmaxf(fmaxf(mred[rl][0], mred[rl][1]), fmaxf(mred[rl][2], mred[rl][3]));
                float sv = expf(acc[m][0][i] - Mr) + expf(acc[m][1][i] - Mr);
                sv += __shfl_xor(sv, 1); sv += __shfl_xor(sv, 2);
                sv += __shfl_xor(sv, 4); sv += __shfl_xor(sv, 8);
                if (fr == 0) sred[rl][wn] = sv;
            }
        __syncthreads();
        if (tid < 128) {
            float Mr = fmaxf(fmaxf(mred[tid][0], mred[tid][1]), fmaxf(mred[tid][2], mred[tid][3]));
            float Sv = sred[tid][0] + sred[tid][1] + sred[tid][2] + sred[tid][3];
            stats[(size_t)(bm + tid) * nchunk + (bn >> 7)] = make_float2(Mr, Sv);
        }
    }
}

// ---------------- phase A: small MFMA GEMM 64x64 tile, BK=64, 256 thr; grid (N/64, 1) ----------------
__global__ __launch_bounds__(256) void gemm_small(const unsigned short* __restrict__ A,
                                                  const unsigned short* __restrict__ Bw,
                                                  const float* __restrict__ bias,
                                                  float* __restrict__ Cout, int M, int N, int K) {
    __shared__ unsigned short As[64][72];
    __shared__ unsigned short Bs[64][72];
    const int bm = blockIdx.y * 64, bn = blockIdx.x * 64;
    const int tid = threadIdx.x, lane = tid & 63, w = tid >> 6;
    const int quad = lane >> 4, fr = lane & 15;
    f32x4 acc0[4] = {}, acc1[4] = {}, acc2[4] = {}, acc3[4] = {};
    f32x4* accs[4] = { acc0, acc1, acc2, acc3 };

    const int srow = tid >> 2, sc16 = (tid & 3) * 16;
    for (int k0 = 0; k0 < K; k0 += 64) {
        const unsigned short* ap = A + (size_t)(bm + srow) * K + k0 + sc16;
        *reinterpret_cast<bf16x8*>(&As[srow][sc16])     = *reinterpret_cast<const bf16x8*>(ap);
        *reinterpret_cast<bf16x8*>(&As[srow][sc16 + 8]) = *reinterpret_cast<const bf16x8*>(ap + 8);
        const unsigned short* bp = Bw + (size_t)(bn + srow) * K + k0 + sc16;
        *reinterpret_cast<bf16x8*>(&Bs[srow][sc16])     = *reinterpret_cast<const bf16x8*>(bp);
        *reinterpret_cast<bf16x8*>(&Bs[srow][sc16 + 8]) = *reinterpret_cast<const bf16x8*>(bp + 8);
        __syncthreads();
        #pragma unroll
        for (int ks = 0; ks < 2; ++ks) {
            const int kg = quad * 8 + 32 * ks;
            bf16x8 bb = *reinterpret_cast<const bf16x8*>(&Bs[16 * w + fr][kg]);
            #pragma unroll
            for (int m = 0; m < 4; ++m) {
                bf16x8 a = *reinterpret_cast<const bf16x8*>(&As[16 * m + fr][kg]);
                accs[m][0] = __builtin_amdgcn_mfma_f32_16x16x32_bf16(a, bb, accs[m][0], 0, 0, 0);
            }
        }
        __syncthreads();
    }
    int col = bn + 16 * w + fr;
    float bv = bias ? bias[col] : 0.f;
    #pragma unroll
    for (int m = 0; m < 4; ++m)
        #pragma unroll
        for (int i = 0; i < 4; ++i) {
            int row = bm + 16 * m + quad * 4 + i;
            Cout[(size_t)row * N + col] = accs[m][0][i] + bv;
        }
}

// ---------------- phase B: scores + softmax + KV-quarter + GRU-quarter ----------------
// grid (4, B), 256 thr. Block (q,b): batch b, H-quarter q (j in [q*256, q*256+256)).
__global__ __launch_bounds__(256) void stepB(const float* __restrict__ ghq,
                                             const unsigned short* __restrict__ keys,
                                             const unsigned short* __restrict__ KV,
                                             const float* __restrict__ va,
                                             const float* __restrict__ va_b,
                                             const float* __restrict__ gi_emb,
                                             float* __restrict__ h,
                                             unsigned short* __restrict__ hbf,
                                             unsigned short* __restrict__ outs_bf,
                                             float* __restrict__ attns,
                                             float* __restrict__ h_final, int t) {
    const int q = blockIdx.x, b = blockIdx.y;
    const int tid = threadIdx.x, lane = tid & 63, wv = tid >> 6;
    __shared__ float ssc[128];
    __shared__ float sw[128];
    __shared__ float red[4][64][13];   // [wave][quad][r0..3 z0..3 n0..3], +1 pad

    // scores: wave wv handles s in [wv*32, +32); lane owns h-chunk [lane*16, +16)
    float qv[16], vv[16];
    {
        const float* qp = ghq + (size_t)b * 4096 + H3 + lane * 16;
        const float* vp = va + lane * 16;
        #pragma unroll
        for (int j = 0; j < 16; ++j) { qv[j] = qp[j]; vv[j] = vp[j]; }
    }
    const float vab = va_b[0];
    const unsigned short* kb = keys + (size_t)b * S * H;
    for (int i = 0; i < 32; ++i) {
        int s = wv * 32 + i;
        const unsigned short* kr = kb + (size_t)s * H + lane * 16;
        ushort8v k0 = *reinterpret_cast<const ushort8v*>(kr);
        ushort8v k1 = *reinterpret_cast<const ushort8v*>(kr + 8);
        float acc = 0.f;
        #pragma unroll
        for (int e = 0; e < 8; ++e) acc += fast_tanh(qv[e] + b2f(k0[e])) * vv[e];
        #pragma unroll
        for (int e = 0; e < 8; ++e) acc += fast_tanh(qv[8 + e] + b2f(k1[e])) * vv[8 + e];
        acc += __shfl_xor(acc, 1);  acc += __shfl_xor(acc, 2);
        acc += __shfl_xor(acc, 4);  acc += __shfl_xor(acc, 8);
        acc += __shfl_xor(acc, 16); acc += __shfl_xor(acc, 32);
        if (lane == 0) ssc[s] = acc + vab;
    }
    __syncthreads();
    // softmax (redundant across the 4 q-blocks; only q==0 writes attns)
    if (tid < 128) {
        float mx = -1e30f;
        #pragma unroll 8
        for (int s = 0; s < 128; ++s) mx = fmaxf(mx, ssc[s]);
        float sum = 0.f;
        #pragma unroll 8
        for (int s = 0; s < 128; ++s) sum += __expf(ssc[s] - mx);
        float wvv = __expf(ssc[tid] - mx) / sum;
        sw[tid] = wvv;
        if (q == 0) attns[((size_t)b * T + t) * S + tid] = wvv;
    }
    __syncthreads();

    // KV quarter: lane owns j-quad j0 = q*256 + lane*4; wave wv sums s in [wv*32,+32)
    const int j0 = q * 256 + lane * 4;
    float ar[4] = {}, az[4] = {}, an[4] = {};
    const unsigned short* kvb = KV + (size_t)b * S * H3 + j0;
    for (int i = 0; i < 32; ++i) {
        int s = wv * 32 + i;
        float ws = sw[s];
        const unsigned short* row = kvb + (size_t)s * H3;
        uint2 u0 = *reinterpret_cast<const uint2*>(row);
        uint2 u1 = *reinterpret_cast<const uint2*>(row + 1024);
        uint2 u2 = *reinterpret_cast<const uint2*>(row + 2048);
        ar[0] += ws * b2f((unsigned short)(u0.x & 0xffff));
        ar[1] += ws * b2f((unsigned short)(u0.x >> 16));
        ar[2] += ws * b2f((unsigned short)(u0.y & 0xffff));
        ar[3] += ws * b2f((unsigned short)(u0.y >> 16));
        az[0] += ws * b2f((unsigned short)(u1.x & 0xffff));
        az[1] += ws * b2f((unsigned short)(u1.x >> 16));
        az[2] += ws * b2f((unsigned short)(u1.y & 0xffff));
        az[3] += ws * b2f((unsigned short)(u1.y >> 16));
        an[0] += ws * b2f((unsigned short)(u2.x & 0xffff));
        an[1] += ws * b2f((unsigned short)(u2.x >> 16));
        an[2] += ws * b2f((unsigned short)(u2.y & 0xffff));
        an[3] += ws * b2f((unsigned short)(u2.y >> 16));
    }
    #pragma unroll
    for (int g = 0; g < 4; ++g) {
        red[wv][lane][g]     = ar[g];
        red[wv][lane][4 + g] = az[g];
        red[wv][lane][8 + g] = an[g];
    }
    __syncthreads();

    // reduce + GRU: thread tid<64 owns quad tid
    if (tid < 64) {
        float rr[4], zz[4], nn[4];
        #pragma unroll
        for (int g = 0; g < 4; ++g) {
            rr[g] = red[0][tid][g] + red[1][tid][g] + red[2][tid][g] + red[3][tid][g];
            zz[g] = red[0][tid][4+g] + red[1][tid][4+g] + red[2][tid][4+g] + red[3][tid][4+g];
            nn[g] = red[0][tid][8+g] + red[1][tid][8+g] + red[2][tid][8+g] + red[3][tid][8+g];
        }
        const int jj = q * 256 + tid * 4;
        const float* ge = gi_emb + ((size_t)t * B + b) * H3;
        const float* gh = ghq + (size_t)b * 4096;
        float geR[4], geZ[4], geN[4], ghR[4], ghZ[4], ghN[4], hv[4];
        *reinterpret_cast<float4*>(geR) = *reinterpret_cast<const float4*>(ge + jj);
        *reinterpret_cast<float4*>(geZ) = *reinterpret_cast<const float4*>(ge + 1024 + jj);
        *reinterpret_cast<float4*>(geN) = *reinterpret_cast<const float4*>(ge + 2048 + jj);
        *reinterpret_cast<float4*>(ghR) = *reinterpret_cast<const float4*>(gh + jj);
        *reinterpret_cast<float4*>(ghZ) = *reinterpret_cast<const float4*>(gh + 1024 + jj);
        *reinterpret_cast<float4*>(ghN) = *reinterpret_cast<const float4*>(gh + 2048 + jj);
        *reinterpret_cast<float4*>(hv)  = *reinterpret_cast<const float4*>(h + (size_t)b * H + jj);
        ushort4 hb;
        unsigned short* hbp = reinterpret_cast<unsigned short*>(&hb);
        #pragma unroll
        for (int i = 0; i < 4; ++i) {
            float r = fast_sigmoid(geR[i] + rr[i] + ghR[i]);
            float z = fast_sigmoid(geZ[i] + zz[i] + ghZ[i]);
            float n = fast_tanh(geN[i] + nn[i] + r * ghN[i]);
            hv[i] = (1.f - z) * n + z * hv[i];
            hbp[i] = f2b(hv[i]);
        }
        *reinterpret_cast<float4*>(h + (size_t)b * H + jj) = *reinterpret_cast<float4*>(hv);
        *reinterpret_cast<ushort4*>(hbf + (size_t)b * H + jj) = hb;
        *reinterpret_cast<ushort4*>(outs_bf + ((size_t)b * T + t) * H + jj) = hb;
        if (t == T - 1)
            *reinterpret_cast<float4*>(h_final + (size_t)b * H + jj) = *reinterpret_cast<float4*>(hv);
    }
}

// ---------------- log-softmax finalize ----------------
__global__ void lse_kernel(const float2* __restrict__ stats, float* __restrict__ lse) {
    const int row = blockIdx.x;
    const int tid = threadIdx.x;   // 256
    __shared__ float shm[256];
    __shared__ float shs[256];
    float mv = -1e30f, sv = 0.f;
    float2 st = make_float2(-1e30f, 0.f);
    if (tid < NCHUNK) { st = stats[(size_t)row * NCHUNK + tid]; mv = st.x; }
    shm[tid] = mv; __syncthreads();
    for (int off = 128; off > 0; off >>= 1) {
        if (tid < off) shm[tid] = fmaxf(shm[tid], shm[tid + off]);
        __syncthreads();
    }
    float M = shm[0]; __syncthreads();
    if (tid < NCHUNK) sv = st.y * expf(st.x - M);
    shs[tid] = sv; __syncthreads();
    for (int off = 128; off > 0; off >>= 1) {
        if (tid < off) shs[tid] += shs[tid + off];
        __syncthreads();
    }
    if (tid == 0) lse[row] = M + logf(shs[0]);
}

__global__ void sub_lse(float* __restrict__ x, const float* __restrict__ lse) {
    const int n4 = B * T * (V / 4);
    float4* p = reinterpret_cast<float4*>(x);
    for (int i = blockIdx.x * 256 + threadIdx.x; i < n4; i += gridDim.x * 256) {
        int row = i / (V / 4);
        float l = lse[row];
        float4 v = p[i];
        v.x -= l; v.y -= l; v.z -= l; v.w -= l;
        p[i] = v;
    }
}

// ---------------- host ----------------

extern "C" void kernel_launch(void* const* d_in, const int* in_sizes, int n_in,
                              void* d_out, int out_size, void* d_ws, size_t ws_size,
                              hipStream_t stream) {
    const float* enc   = (const float*)d_in[0];
    const float* h0    = (const float*)d_in[1];
    const int*   tgt   = (const int*)d_in[2];
    const float* emb   = (const float*)d_in[3];
    const float* Wa_w  = (const float*)d_in[4];
    const float* Wa_b  = (const float*)d_in[5];
    const float* Ua_w  = (const float*)d_in[6];
    const float* Ua_b  = (const float*)d_in[7];
    const float* Va_w  = (const float*)d_in[8];
    const float* Va_b  = (const float*)d_in[9];
    const float* gwi   = (const float*)d_in[10];
    const float* gwh   = (const float*)d_in[11];
    const float* gbi   = (const float*)d_in[12];
    const float* gbh   = (const float*)d_in[13];
    const float* out_w = (const float*)d_in[14];
    const float* out_b = (const float*)d_in[15];

    float* out       = (float*)d_out;
    float* log_probs = out;                          // [B*T, V]
    float* h_final   = out + (size_t)B * T * V;      // [B, H]
    float* attns     = h_final + (size_t)B * H;      // [B, T, S]

    char* pp = (char*)d_ws;
    auto alloc = [&](size_t bytes) { char* r = pp; pp += (bytes + 255) & ~(size_t)255; return r; };
    unsigned short* ua_bf   = (unsigned short*)alloc((size_t)B * S * H * 2);
    unsigned short* enc_bf  = (unsigned short*)alloc((size_t)B * S * H * 2);
    unsigned short* outw_bf = (unsigned short*)alloc((size_t)V * H * 2);
    unsigned short* KV      = (unsigned short*)alloc((size_t)B * S * H3 * 2);
    unsigned short* Ua_bf   = (unsigned short*)alloc((size_t)H * H * 2);
    unsigned short* Wcat    = (unsigned short*)alloc((size_t)4096 * H * 2);
    unsigned short* Wctx    = (unsigned short*)alloc((size_t)H3 * H * 2);
    unsigned short* Wemb    = (unsigned short*)alloc((size_t)H3 * H * 2);
    float*          catbias = (float*)alloc(4096 * 4);
    unsigned short* embg    = (unsigned short*)alloc((size_t)T * B * H * 2);
    float*          gi_emb  = (float*)alloc((size_t)T * B * H3 * 4);
    float*          hbuf    = (float*)alloc((size_t)B * H * 4);
    unsigned short* hbf     = (unsigned short*)alloc((size_t)B * H * 2);
    float*          ghq     = (float*)alloc((size_t)B * 4096 * 4);
    unsigned short* outs_bf = (unsigned short*)alloc((size_t)B * T * H * 2);
    float2*         stats   = (float2*)alloc((size_t)B * T * NCHUNK * 8);
    float*          lse     = (float*)alloc((size_t)B * T * 4);

    // all conversions/builds in one launch (incl. hbf init)
    prep_kernel<<<52176, 256, 0, stream>>>(enc, enc_bf, out_w, outw_bf, Ua_w, Ua_bf,
                                           gwh, Wa_w, Wcat, gwi, Wemb, Wctx,
                                           gbh, Wa_b, catbias, emb, tgt, embg, h0, hbf);
    hipMemcpyAsync(hbuf, h0, (size_t)B * H * sizeof(float), hipMemcpyDeviceToDevice, stream);

    // ua_keys = enc @ Ua_w^T + Ua_b -> bf16 [B*S, H]
    gemm_big<1, 0><<<(B * S / 128) * (H / 128), 512, 0, stream>>>(
        enc_bf, Ua_bf, Ua_b, ua_bf, nullptr, B * S, H, H);
    // KV = enc @ Wctx^T -> bf16 [B*S, 3072]
    gemm_big<1, 0><<<(B * S / 128) * (H3 / 128), 512, 0, stream>>>(
        enc_bf, Wctx, nullptr, KV, nullptr, B * S, H3, H);
    // gi_emb = embg @ Wemb^T + gbi -> fp32 [T*B, 3072]
    gemm_big<0, 0><<<(T * B / 128) * (H3 / 128), 512, 0, stream>>>(
        embg, Wemb, gbi, gi_emb, nullptr, T * B, H3, H);

    for (int t = 0; t < T; ++t) {
        // phase A: [gh | q] = h @ [gwh; Wa_w]^T + [gbh; Wa_b]  [64, 4096]
        gemm_small<<<dim3(4096 / 64, 1), 256, 0, stream>>>(hbf, Wcat, catbias, ghq, B, 4096, H);
        // phase B: 4 blocks per batch
        stepB<<<dim3(4, B), 256, 0, stream>>>(ghq, ua_bf, KV, Va_w, Va_b, gi_emb,
                                              hbuf, hbf, outs_bf, attns, h_final, t);
    }

    // logits = outs @ out_w^T + out_b  [640, 32000] + fused softmax stats
    gemm_big<0, 1><<<(B * T / 128) * (V / 128), 512, 0, stream>>>(
        outs_bf, outw_bf, out_b, log_probs, stats, B * T, V, H);
    lse_kernel<<<B * T, 256, 0, stream>>>(stats, lse);
    sub_lse<<<2048, 256, 0, stream>>>(log_probs, lse);
}

// Round 9
// 711.560 us; speedup vs baseline: 1.7216x; 1.2688x over previous
//
#include <hip/hip_runtime.h>
#include <hip/hip_bf16.h>
#include <cstddef>

#define B 64
#define S 128
#define H 1024
#define V 32000
#define T 10
#define H3 3072
#define NCHUNK 250

typedef __bf16 bf16x8 __attribute__((ext_vector_type(8)));
typedef float f32x4 __attribute__((ext_vector_type(4)));
typedef unsigned short ushort8v __attribute__((ext_vector_type(8)));

__device__ inline unsigned short f2b(float f) {
    __hip_bfloat16 h = __float2bfloat16(f);
    return *reinterpret_cast<unsigned short*>(&h);
}
__device__ inline float b2f(unsigned short u) {
    return __uint_as_float(((unsigned)u) << 16);
}
__device__ inline float fast_tanh(float x) {
    float e = __expf(2.f * x);
    return 1.f - 2.f * __builtin_amdgcn_rcpf(e + 1.f);
}
__device__ inline float fast_sigmoid(float x) {
    return __builtin_amdgcn_rcpf(1.f + __expf(-x));
}

// bijective XCD swizzle (m204); requires nwg % 8 == 0 here (all call sites satisfy)
__device__ inline int xcd_swz(int orig, int nwg) {
    int q = nwg >> 3, r = nwg & 7;
    int xcd = orig & 7, idx = orig >> 3;
    int base = (xcd < r) ? xcd * (q + 1) : r * (q + 1) + (xcd - r) * q;
    return base + idx;
}

// ---------------- unified prep kernel ----------------
// [0,8192) enc | [8192,40192) out_w | [40192,41216) Ua | [41216,45312) Wcat
// [45312,48384) Wemb | [48384,51456) Wctx | [51456,51472) catbias
// [51472,52112) embg | [52112,52176) hbf | [52176,52240) hbuf
#define PREP_NB 52240
__global__ void prep_kernel(const float* __restrict__ enc, unsigned short* __restrict__ enc_bf,
                            const float* __restrict__ out_w, unsigned short* __restrict__ outw_bf,
                            const float* __restrict__ Ua_w, unsigned short* __restrict__ Ua_bf,
                            const float* __restrict__ gwh, const float* __restrict__ Wa_w,
                            unsigned short* __restrict__ Wcat,
                            const float* __restrict__ gwi,
                            unsigned short* __restrict__ Wemb, unsigned short* __restrict__ Wctx,
                            const float* __restrict__ gbh, const float* __restrict__ Wa_b,
                            float* __restrict__ catbias,
                            const float* __restrict__ emb, const int* __restrict__ tgt,
                            unsigned short* __restrict__ embg,
                            const float* __restrict__ h0, unsigned short* __restrict__ hbf,
                            float* __restrict__ hbuf) {
    const int bid = blockIdx.x, tid = threadIdx.x;
    if (bid < 8192) {
        int i = bid * 256 + tid;
        float4 v = reinterpret_cast<const float4*>(enc)[i];
        ushort4 o = { f2b(v.x), f2b(v.y), f2b(v.z), f2b(v.w) };
        reinterpret_cast<ushort4*>(enc_bf)[i] = o;
    } else if (bid < 40192) {
        int i = (bid - 8192) * 256 + tid;
        float4 v = reinterpret_cast<const float4*>(out_w)[i];
        ushort4 o = { f2b(v.x), f2b(v.y), f2b(v.z), f2b(v.w) };
        reinterpret_cast<ushort4*>(outw_bf)[i] = o;
    } else if (bid < 41216) {
        int i = (bid - 40192) * 256 + tid;
        float4 v = reinterpret_cast<const float4*>(Ua_w)[i];
        ushort4 o = { f2b(v.x), f2b(v.y), f2b(v.z), f2b(v.w) };
        reinterpret_cast<ushort4*>(Ua_bf)[i] = o;
    } else if (bid < 45312) {
        int i = (bid - 41216) * 256 + tid;
        int e = i * 4, n = e >> 10, k = e & 1023;
        const float* src = (n < H3) ? (gwh + (size_t)n * H + k) : (Wa_w + (size_t)(n - H3) * H + k);
        float4 v = *reinterpret_cast<const float4*>(src);
        ushort4 o = { f2b(v.x), f2b(v.y), f2b(v.z), f2b(v.w) };
        reinterpret_cast<ushort4*>(Wcat)[i] = o;
    } else if (bid < 48384) {
        int i = (bid - 45312) * 256 + tid;
        int e = i * 4, n = e >> 10, k = e & 1023;
        float4 v = *reinterpret_cast<const float4*>(gwi + (size_t)n * 2 * H + k);
        ushort4 o = { f2b(v.x), f2b(v.y), f2b(v.z), f2b(v.w) };
        reinterpret_cast<ushort4*>(Wemb)[i] = o;
    } else if (bid < 51456) {
        int i = (bid - 48384) * 256 + tid;
        int e = i * 4, n = e >> 10, k = e & 1023;
        float4 v = *reinterpret_cast<const float4*>(gwi + (size_t)n * 2 * H + H + k);
        ushort4 o = { f2b(v.x), f2b(v.y), f2b(v.z), f2b(v.w) };
        reinterpret_cast<ushort4*>(Wctx)[i] = o;
    } else if (bid < 51472) {
        int n = (bid - 51456) * 256 + tid;
        catbias[n] = (n < H3) ? gbh[n] : Wa_b[n - H3];
    } else if (bid < 52112) {
        int i = (bid - 51472) * 256 + tid;
        int e = i * 4;
        int t = e >> 16, rem = e & 65535;
        int b = rem >> 10, j = rem & 1023;
        int tok = (t == 0) ? 0 : tgt[b * T + (t - 1)];
        float4 v = *reinterpret_cast<const float4*>(emb + (size_t)tok * H + j);
        ushort4 o = { f2b(v.x), f2b(v.y), f2b(v.z), f2b(v.w) };
        *reinterpret_cast<ushort4*>(embg + ((size_t)t * B + b) * H + j) = o;
    } else if (bid < 52176) {
        int i = (bid - 52112) * 256 + tid;
        float4 v = reinterpret_cast<const float4*>(h0)[i];
        ushort4 o = { f2b(v.x), f2b(v.y), f2b(v.z), f2b(v.w) };
        reinterpret_cast<ushort4*>(hbf)[i] = o;
    } else {
        int i = (bid - 52176) * 256 + tid;
        reinterpret_cast<float4*>(hbuf)[i] = reinterpret_cast<const float4*>(h0)[i];
    }
}

// ---------------- merged 3-GEMM kernel (ua + KV + gi_emb), K=1024 fixed ----------------
struct GemmDesc {
    const unsigned short* A;
    const unsigned short* Bw;
    const float* bias;
    void* C;
    int M, N, out_bf16;
};

__global__ __launch_bounds__(512) void gemm3_kernel(GemmDesc d0, GemmDesc d1, GemmDesc d2) {
    __shared__ unsigned short As[128][72];
    __shared__ unsigned short Bs[128][72];
    const int bid = blockIdx.x;
    GemmDesc d; int local, nwg;
    if (bid < 512)       { d = d0; local = bid;        nwg = 512;  }
    else if (bid < 2048) { d = d1; local = bid - 512;  nwg = 1536; }
    else                 { d = d2; local = bid - 2048; nwg = 120;  }
    local = xcd_swz(local, nwg);
    const int mtiles = d.M >> 7;
    const int bm = (local % mtiles) << 7, bn = (local / mtiles) << 7;
    const int tid = threadIdx.x, lane = tid & 63, w = tid >> 6;
    const int wm = w >> 2, wn = w & 3;
    const int quad = lane >> 4, fr = lane & 15;
    f32x4 acc[4][2] = {};

    const int srow = tid >> 2, sc16 = (tid & 3) * 16;
    for (int k0 = 0; k0 < H; k0 += 64) {
        const unsigned short* ap = d.A + (size_t)(bm + srow) * H + k0 + sc16;
        *reinterpret_cast<bf16x8*>(&As[srow][sc16])     = *reinterpret_cast<const bf16x8*>(ap);
        *reinterpret_cast<bf16x8*>(&As[srow][sc16 + 8]) = *reinterpret_cast<const bf16x8*>(ap + 8);
        const unsigned short* bp = d.Bw + (size_t)(bn + srow) * H + k0 + sc16;
        *reinterpret_cast<bf16x8*>(&Bs[srow][sc16])     = *reinterpret_cast<const bf16x8*>(bp);
        *reinterpret_cast<bf16x8*>(&Bs[srow][sc16 + 8]) = *reinterpret_cast<const bf16x8*>(bp + 8);
        __syncthreads();
        #pragma unroll
        for (int ks = 0; ks < 2; ++ks) {
            const int kg = quad * 8 + 32 * ks;
            bf16x8 a[4], bb[2];
            #pragma unroll
            for (int m = 0; m < 4; ++m)
                a[m] = *reinterpret_cast<const bf16x8*>(&As[64 * wm + 16 * m + fr][kg]);
            #pragma unroll
            for (int n = 0; n < 2; ++n)
                bb[n] = *reinterpret_cast<const bf16x8*>(&Bs[32 * wn + 16 * n + fr][kg]);
            #pragma unroll
            for (int m = 0; m < 4; ++m)
                #pragma unroll
                for (int n = 0; n < 2; ++n)
                    acc[m][n] = __builtin_amdgcn_mfma_f32_16x16x32_bf16(a[m], bb[n], acc[m][n], 0, 0, 0);
        }
        __syncthreads();
    }
    #pragma unroll
    for (int n = 0; n < 2; ++n) {
        int col = bn + 32 * wn + 16 * n + fr;
        float bv = d.bias ? d.bias[col] : 0.f;
        #pragma unroll
        for (int m = 0; m < 4; ++m)
            #pragma unroll
            for (int i = 0; i < 4; ++i) {
                int row = bm + 64 * wm + 16 * m + quad * 4 + i;
                float v = acc[m][n][i] + bv;
                if (d.out_bf16)
                    ((unsigned short*)d.C)[(size_t)row * d.N + col] = f2b(v);
                else
                    ((float*)d.C)[(size_t)row * d.N + col] = v;
            }
    }
}

// ---------------- logits GEMM: 128x128, BK=64, swizzled 1D grid, fused softmax stats ----------------
__global__ __launch_bounds__(512) void gemm_logits(const unsigned short* __restrict__ A,
                                                   const unsigned short* __restrict__ Bw,
                                                   const float* __restrict__ bias,
                                                   float* __restrict__ Cout,
                                                   float2* __restrict__ stats,
                                                   int M, int N, int K) {
    __shared__ unsigned short As[128][72];
    __shared__ unsigned short Bs[128][72];
    __shared__ float mred[128][4];
    __shared__ float sred[128][4];
    const int wg = xcd_swz(blockIdx.x, gridDim.x);
    const int mtiles = M >> 7;
    const int bm = (wg % mtiles) << 7, bn = (wg / mtiles) << 7;
    const int tid = threadIdx.x, lane = tid & 63, w = tid >> 6;
    const int wm = w >> 2, wn = w & 3;
    const int quad = lane >> 4, fr = lane & 15;
    f32x4 acc[4][2] = {};

    const int srow = tid >> 2, sc16 = (tid & 3) * 16;
    for (int k0 = 0; k0 < K; k0 += 64) {
        const unsigned short* ap = A + (size_t)(bm + srow) * K + k0 + sc16;
        *reinterpret_cast<bf16x8*>(&As[srow][sc16])     = *reinterpret_cast<const bf16x8*>(ap);
        *reinterpret_cast<bf16x8*>(&As[srow][sc16 + 8]) = *reinterpret_cast<const bf16x8*>(ap + 8);
        const unsigned short* bp = Bw + (size_t)(bn + srow) * K + k0 + sc16;
        *reinterpret_cast<bf16x8*>(&Bs[srow][sc16])     = *reinterpret_cast<const bf16x8*>(bp);
        *reinterpret_cast<bf16x8*>(&Bs[srow][sc16 + 8]) = *reinterpret_cast<const bf16x8*>(bp + 8);
        __syncthreads();
        #pragma unroll
        for (int ks = 0; ks < 2; ++ks) {
            const int kg = quad * 8 + 32 * ks;
            bf16x8 a[4], bb[2];
            #pragma unroll
            for (int m = 0; m < 4; ++m)
                a[m] = *reinterpret_cast<const bf16x8*>(&As[64 * wm + 16 * m + fr][kg]);
            #pragma unroll
            for (int n = 0; n < 2; ++n)
                bb[n] = *reinterpret_cast<const bf16x8*>(&Bs[32 * wn + 16 * n + fr][kg]);
            #pragma unroll
            for (int m = 0; m < 4; ++m)
                #pragma unroll
                for (int n = 0; n < 2; ++n)
                    acc[m][n] = __builtin_amdgcn_mfma_f32_16x16x32_bf16(a[m], bb[n], acc[m][n], 0, 0, 0);
        }
        __syncthreads();
    }

    #pragma unroll
    for (int n = 0; n < 2; ++n) {
        int col = bn + 32 * wn + 16 * n + fr;
        float bv = bias[col];
        #pragma unroll
        for (int m = 0; m < 4; ++m)
            #pragma unroll
            for (int i = 0; i < 4; ++i) {
                int row = bm + 64 * wm + 16 * m + quad * 4 + i;
                float v = acc[m][n][i] + bv;
                Cout[(size_t)row * N + col] = v;
                acc[m][n][i] = v;
            }
    }

    const int nchunk = N >> 7;
    #pragma unroll
    for (int m = 0; m < 4; ++m)
        #pragma unroll
        for (int i = 0; i < 4; ++i) {
            float x = fmaxf(acc[m][0][i], acc[m][1][i]);
            x = fmaxf(x, __shfl_xor(x, 1)); x = fmaxf(x, __shfl_xor(x, 2));
            x = fmaxf(x, __shfl_xor(x, 4)); x = fmaxf(x, __shfl_xor(x, 8));
            if (fr == 0) mred[64 * wm + 16 * m + quad * 4 + i][wn] = x;
        }
    __syncthreads();
    #pragma unroll
    for (int m = 0; m < 4; ++m)
        #pragma unroll
        for (int i = 0; i < 4; ++i) {
            int rl = 64 * wm + 16 * m + quad * 4 + i;
            float Mr = fmaxf(fmaxf(mred[rl][0], mred[rl][1]), fmaxf(mred[rl][2], mred[rl][3]));
            float sv = expf(acc[m][0][i] - Mr) + expf(acc[m][1][i] - Mr);
            sv += __shfl_xor(sv, 1); sv += __shfl_xor(sv, 2);
            sv += __shfl_xor(sv, 4); sv += __shfl_xor(sv, 8);
            if (fr == 0) sred[rl][wn] = sv;
        }
    __syncthreads();
    if (tid < 128) {
        float Mr = fmaxf(fmaxf(mred[tid][0], mred[tid][1]), fmaxf(mred[tid][2], mred[tid][3]));
        float Sv = sred[tid][0] + sred[tid][1] + sred[tid][2] + sred[tid][3];
        stats[(size_t)(bm + tid) * nchunk + (bn >> 7)] = make_float2(Mr, Sv);
    }
}

// ---------------- phase A: 64x32 tile, BK=128, grid 128, 256 thr ----------------
__global__ __launch_bounds__(256) void gemm_smallA(const unsigned short* __restrict__ A,
                                                   const unsigned short* __restrict__ Bw,
                                                   const float* __restrict__ bias,
                                                   float* __restrict__ Cout) {
    __shared__ unsigned short As[64][136];
    __shared__ unsigned short Bs[32][136];
    const int bn = blockIdx.x * 32;            // N = 4096
    const int tid = threadIdx.x, lane = tid & 63, w = tid >> 6;
    const int quad = lane >> 4, fr = lane & 15;
    f32x4 acc[2] = {};

    const int srA = tid >> 2, scA = (tid & 3) * 32;  // 64 rows, 32 halves each
    const int srB = tid >> 3, scB = (tid & 7) * 16;  // 32 rows, 16 halves each
    for (int k0 = 0; k0 < H; k0 += 128) {
        const unsigned short* ap = A + (size_t)srA * H + k0 + scA;
        #pragma unroll
        for (int u = 0; u < 4; ++u)
            *reinterpret_cast<bf16x8*>(&As[srA][scA + 8 * u]) =
                *reinterpret_cast<const bf16x8*>(ap + 8 * u);
        const unsigned short* bp = Bw + (size_t)(bn + srB) * H + k0 + scB;
        *reinterpret_cast<bf16x8*>(&Bs[srB][scB])     = *reinterpret_cast<const bf16x8*>(bp);
        *reinterpret_cast<bf16x8*>(&Bs[srB][scB + 8]) = *reinterpret_cast<const bf16x8*>(bp + 8);
        __syncthreads();
        #pragma unroll
        for (int ks = 0; ks < 4; ++ks) {
            const int kg = quad * 8 + 32 * ks;
            bf16x8 a = *reinterpret_cast<const bf16x8*>(&As[16 * w + fr][kg]);
            #pragma unroll
            for (int n = 0; n < 2; ++n) {
                bf16x8 bb = *reinterpret_cast<const bf16x8*>(&Bs[16 * n + fr][kg]);
                acc[n] = __builtin_amdgcn_mfma_f32_16x16x32_bf16(a, bb, acc[n], 0, 0, 0);
            }
        }
        __syncthreads();
    }
    #pragma unroll
    for (int n = 0; n < 2; ++n) {
        int col = bn + 16 * n + fr;
        float bv = bias[col];
        #pragma unroll
        for (int i = 0; i < 4; ++i) {
            int row = 16 * w + quad * 4 + i;
            Cout[(size_t)row * 4096 + col] = acc[n][i] + bv;
        }
    }
}

// ---------------- phase B: scores + softmax + KV-quarter + GRU-quarter ----------------
__global__ __launch_bounds__(256) void stepB(const float* __restrict__ ghq,
                                             const unsigned short* __restrict__ keys,
                                             const unsigned short* __restrict__ KV,
                                             const float* __restrict__ va,
                                             const float* __restrict__ va_b,
                                             const float* __restrict__ gi_emb,
                                             float* __restrict__ h,
                                             unsigned short* __restrict__ hbf,
                                             unsigned short* __restrict__ outs_bf,
                                             float* __restrict__ attns,
                                             float* __restrict__ h_final, int t) {
    const int q = blockIdx.x, b = blockIdx.y;
    const int tid = threadIdx.x, lane = tid & 63, wv = tid >> 6;
    __shared__ float ssc[128];
    __shared__ float sw[128];
    __shared__ float red[4][64][13];

    float qv[16], vv[16];
    {
        const float* qp = ghq + (size_t)b * 4096 + H3 + lane * 16;
        const float* vp = va + lane * 16;
        #pragma unroll
        for (int j = 0; j < 16; ++j) { qv[j] = qp[j]; vv[j] = vp[j]; }
    }
    const float vab = va_b[0];
    const unsigned short* kb = keys + (size_t)b * S * H;
    // scores, 2 s per iteration for MLP
    for (int i = 0; i < 32; i += 2) {
        int s0 = wv * 32 + i;
        const unsigned short* kr0 = kb + (size_t)s0 * H + lane * 16;
        const unsigned short* kr1 = kr0 + H;
        ushort8v k00 = *reinterpret_cast<const ushort8v*>(kr0);
        ushort8v k01 = *reinterpret_cast<const ushort8v*>(kr0 + 8);
        ushort8v k10 = *reinterpret_cast<const ushort8v*>(kr1);
        ushort8v k11 = *reinterpret_cast<const ushort8v*>(kr1 + 8);
        float a0 = 0.f, a1 = 0.f;
        #pragma unroll
        for (int e = 0; e < 8; ++e) {
            a0 += fast_tanh(qv[e] + b2f(k00[e])) * vv[e];
            a1 += fast_tanh(qv[e] + b2f(k10[e])) * vv[e];
        }
        #pragma unroll
        for (int e = 0; e < 8; ++e) {
            a0 += fast_tanh(qv[8 + e] + b2f(k01[e])) * vv[8 + e];
            a1 += fast_tanh(qv[8 + e] + b2f(k11[e])) * vv[8 + e];
        }
        a0 += __shfl_xor(a0, 1);  a1 += __shfl_xor(a1, 1);
        a0 += __shfl_xor(a0, 2);  a1 += __shfl_xor(a1, 2);
        a0 += __shfl_xor(a0, 4);  a1 += __shfl_xor(a1, 4);
        a0 += __shfl_xor(a0, 8);  a1 += __shfl_xor(a1, 8);
        a0 += __shfl_xor(a0, 16); a1 += __shfl_xor(a1, 16);
        a0 += __shfl_xor(a0, 32); a1 += __shfl_xor(a1, 32);
        if (lane == 0) { ssc[s0] = a0 + vab; ssc[s0 + 1] = a1 + vab; }
    }
    __syncthreads();
    if (tid < 128) {
        float mx = -1e30f;
        #pragma unroll 8
        for (int s = 0; s < 128; ++s) mx = fmaxf(mx, ssc[s]);
        float sum = 0.f;
        #pragma unroll 8
        for (int s = 0; s < 128; ++s) sum += __expf(ssc[s] - mx);
        float wvv = __expf(ssc[tid] - mx) / sum;
        sw[tid] = wvv;
        if (q == 0) attns[((size_t)b * T + t) * S + tid] = wvv;
    }
    __syncthreads();

    // KV quarter: 2 s per iteration
    const int j0 = q * 256 + lane * 4;
    float ar[4] = {}, az[4] = {}, an[4] = {};
    const unsigned short* kvb = KV + (size_t)b * S * H3 + j0;
    for (int i = 0; i < 32; i += 2) {
        int s0 = wv * 32 + i;
        float w0 = sw[s0], w1 = sw[s0 + 1];
        const unsigned short* r0 = kvb + (size_t)s0 * H3;
        const unsigned short* r1 = r0 + H3;
        uint2 u0a = *reinterpret_cast<const uint2*>(r0);
        uint2 u1a = *reinterpret_cast<const uint2*>(r0 + 1024);
        uint2 u2a = *reinterpret_cast<const uint2*>(r0 + 2048);
        uint2 u0b = *reinterpret_cast<const uint2*>(r1);
        uint2 u1b = *reinterpret_cast<const uint2*>(r1 + 1024);
        uint2 u2b = *reinterpret_cast<const uint2*>(r1 + 2048);
        ar[0] += w0 * b2f((unsigned short)(u0a.x & 0xffff)) + w1 * b2f((unsigned short)(u0b.x & 0xffff));
        ar[1] += w0 * b2f((unsigned short)(u0a.x >> 16))    + w1 * b2f((unsigned short)(u0b.x >> 16));
        ar[2] += w0 * b2f((unsigned short)(u0a.y & 0xffff)) + w1 * b2f((unsigned short)(u0b.y & 0xffff));
        ar[3] += w0 * b2f((unsigned short)(u0a.y >> 16))    + w1 * b2f((unsigned short)(u0b.y >> 16));
        az[0] += w0 * b2f((unsigned short)(u1a.x & 0xffff)) + w1 * b2f((unsigned short)(u1b.x & 0xffff));
        az[1] += w0 * b2f((unsigned short)(u1a.x >> 16))    + w1 * b2f((unsigned short)(u1b.x >> 16));
        az[2] += w0 * b2f((unsigned short)(u1a.y & 0xffff)) + w1 * b2f((unsigned short)(u1b.y & 0xffff));
        az[3] += w0 * b2f((unsigned short)(u1a.y >> 16))    + w1 * b2f((unsigned short)(u1b.y >> 16));
        an[0] += w0 * b2f((unsigned short)(u2a.x & 0xffff)) + w1 * b2f((unsigned short)(u2b.x & 0xffff));
        an[1] += w0 * b2f((unsigned short)(u2a.x >> 16))    + w1 * b2f((unsigned short)(u2b.x >> 16));
        an[2] += w0 * b2f((unsigned short)(u2a.y & 0xffff)) + w1 * b2f((unsigned short)(u2b.y & 0xffff));
        an[3] += w0 * b2f((unsigned short)(u2a.y >> 16))    + w1 * b2f((unsigned short)(u2b.y >> 16));
    }
    #pragma unroll
    for (int g = 0; g < 4; ++g) {
        red[wv][lane][g]     = ar[g];
        red[wv][lane][4 + g] = az[g];
        red[wv][lane][8 + g] = an[g];
    }
    __syncthreads();

    if (tid < 64) {
        float rr[4], zz[4], nn[4];
        #pragma unroll
        for (int g = 0; g < 4; ++g) {
            rr[g] = red[0][tid][g] + red[1][tid][g] + red[2][tid][g] + red[3][tid][g];
            zz[g] = red[0][tid][4+g] + red[1][tid][4+g] + red[2][tid][4+g] + red[3][tid][4+g];
            nn[g] = red[0][tid][8+g] + red[1][tid][8+g] + red[2][tid][8+g] + red[3][tid][8+g];
        }
        const int jj = q * 256 + tid * 4;
        const float* ge = gi_emb + ((size_t)t * B + b) * H3;
        const float* gh = ghq + (size_t)b * 4096;
        float geR[4], geZ[4], geN[4], ghR[4], ghZ[4], ghN[4], hv[4];
        *reinterpret_cast<float4*>(geR) = *reinterpret_cast<const float4*>(ge + jj);
        *reinterpret_cast<float4*>(geZ) = *reinterpret_cast<const float4*>(ge + 1024 + jj);
        *reinterpret_cast<float4*>(geN) = *reinterpret_cast<const float4*>(ge + 2048 + jj);
        *reinterpret_cast<float4*>(ghR) = *reinterpret_cast<const float4*>(gh + jj);
        *reinterpret_cast<float4*>(ghZ) = *reinterpret_cast<const float4*>(gh + 1024 + jj);
        *reinterpret_cast<float4*>(ghN) = *reinterpret_cast<const float4*>(gh + 2048 + jj);
        *reinterpret_cast<float4*>(hv)  = *reinterpret_cast<const float4*>(h + (size_t)b * H + jj);
        ushort4 hb;
        unsigned short* hbp = reinterpret_cast<unsigned short*>(&hb);
        #pragma unroll
        for (int i = 0; i < 4; ++i) {
            float r = fast_sigmoid(geR[i] + rr[i] + ghR[i]);
            float z = fast_sigmoid(geZ[i] + zz[i] + ghZ[i]);
            float n = fast_tanh(geN[i] + nn[i] + r * ghN[i]);
            hv[i] = (1.f - z) * n + z * hv[i];
            hbp[i] = f2b(hv[i]);
        }
        *reinterpret_cast<float4*>(h + (size_t)b * H + jj) = *reinterpret_cast<float4*>(hv);
        *reinterpret_cast<ushort4*>(hbf + (size_t)b * H + jj) = hb;
        *reinterpret_cast<ushort4*>(outs_bf + ((size_t)b * T + t) * H + jj) = hb;
        if (t == T - 1)
            *reinterpret_cast<float4*>(h_final + (size_t)b * H + jj) = *reinterpret_cast<float4*>(hv);
    }
}

// ---------------- fused LSE + subtract (one launch, per-row block) ----------------
__global__ void lsesub_kernel(const float2* __restrict__ stats, float* __restrict__ x) {
    const int row = blockIdx.x;            // 640
    const int tid = threadIdx.x;           // 256
    __shared__ float shm[256];
    __shared__ float shs[256];
    float mv = -1e30f, sv = 0.f;
    float2 st = make_float2(-1e30f, 0.f);
    if (tid < NCHUNK) { st = stats[(size_t)row * NCHUNK + tid]; mv = st.x; }
    shm[tid] = mv; __syncthreads();
    for (int off = 128; off > 0; off >>= 1) {
        if (tid < off) shm[tid] = fmaxf(shm[tid], shm[tid + off]);
        __syncthreads();
    }
    float M = shm[0]; __syncthreads();
    if (tid < NCHUNK) sv = st.y * expf(st.x - M);
    shs[tid] = sv; __syncthreads();
    for (int off = 128; off > 0; off >>= 1) {
        if (tid < off) shs[tid] += shs[tid + off];
        __syncthreads();
    }
    float L = M + logf(shs[0]);
    __syncthreads();
    float4* p = reinterpret_cast<float4*>(x + (size_t)row * V);
    for (int i = tid; i < V / 4; i += 256) {
        float4 v = p[i];
        v.x -= L; v.y -= L; v.z -= L; v.w -= L;
        p[i] = v;
    }
}

// ---------------- host ----------------

extern "C" void kernel_launch(void* const* d_in, const int* in_sizes, int n_in,
                              void* d_out, int out_size, void* d_ws, size_t ws_size,
                              hipStream_t stream) {
    const float* enc   = (const float*)d_in[0];
    const float* h0    = (const float*)d_in[1];
    const int*   tgt   = (const int*)d_in[2];
    const float* emb   = (const float*)d_in[3];
    const float* Wa_w  = (const float*)d_in[4];
    const float* Wa_b  = (const float*)d_in[5];
    const float* Ua_w  = (const float*)d_in[6];
    const float* Ua_b  = (const float*)d_in[7];
    const float* Va_w  = (const float*)d_in[8];
    const float* Va_b  = (const float*)d_in[9];
    const float* gwi   = (const float*)d_in[10];
    const float* gwh   = (const float*)d_in[11];
    const float* gbi   = (const float*)d_in[12];
    const float* gbh   = (const float*)d_in[13];
    const float* out_w = (const float*)d_in[14];
    const float* out_b = (const float*)d_in[15];

    float* out       = (float*)d_out;
    float* log_probs = out;                          // [B*T, V]
    float* h_final   = out + (size_t)B * T * V;      // [B, H]
    float* attns     = h_final + (size_t)B * H;      // [B, T, S]

    char* pp = (char*)d_ws;
    auto alloc = [&](size_t bytes) { char* r = pp; pp += (bytes + 255) & ~(size_t)255; return r; };
    unsigned short* ua_bf   = (unsigned short*)alloc((size_t)B * S * H * 2);
    unsigned short* enc_bf  = (unsigned short*)alloc((size_t)B * S * H * 2);
    unsigned short* outw_bf = (unsigned short*)alloc((size_t)V * H * 2);
    unsigned short* KV      = (unsigned short*)alloc((size_t)B * S * H3 * 2);
    unsigned short* Ua_bf   = (unsigned short*)alloc((size_t)H * H * 2);
    unsigned short* Wcat    = (unsigned short*)alloc((size_t)4096 * H * 2);
    unsigned short* Wctx    = (unsigned short*)alloc((size_t)H3 * H * 2);
    unsigned short* Wemb    = (unsigned short*)alloc((size_t)H3 * H * 2);
    float*          catbias = (float*)alloc(4096 * 4);
    unsigned short* embg    = (unsigned short*)alloc((size_t)T * B * H * 2);
    float*          gi_emb  = (float*)alloc((size_t)T * B * H3 * 4);
    float*          hbuf    = (float*)alloc((size_t)B * H * 4);
    unsigned short* hbf     = (unsigned short*)alloc((size_t)B * H * 2);
    float*          ghq     = (float*)alloc((size_t)B * 4096 * 4);
    unsigned short* outs_bf = (unsigned short*)alloc((size_t)B * T * H * 2);
    float2*         stats   = (float2*)alloc((size_t)B * T * NCHUNK * 8);

    // all conversions/builds/copies in one launch
    prep_kernel<<<PREP_NB, 256, 0, stream>>>(enc, enc_bf, out_w, outw_bf, Ua_w, Ua_bf,
                                             gwh, Wa_w, Wcat, gwi, Wemb, Wctx,
                                             gbh, Wa_b, catbias, emb, tgt, embg,
                                             h0, hbf, hbuf);

    // ua_keys / KV / gi_emb in ONE launch
    GemmDesc d0 = { enc_bf, Ua_bf, Ua_b, (void*)ua_bf,  B * S, H,  1 };
    GemmDesc d1 = { enc_bf, Wctx,  nullptr, (void*)KV,  B * S, H3, 1 };
    GemmDesc d2 = { embg,   Wemb,  gbi, (void*)gi_emb,  T * B, H3, 0 };
    gemm3_kernel<<<2168, 512, 0, stream>>>(d0, d1, d2);

    for (int t = 0; t < T; ++t) {
        gemm_smallA<<<128, 256, 0, stream>>>(hbf, Wcat, catbias, ghq);
        stepB<<<dim3(4, B), 256, 0, stream>>>(ghq, ua_bf, KV, Va_w, Va_b, gi_emb,
                                              hbuf, hbf, outs_bf, attns, h_final, t);
    }

    // logits + fused softmax stats
    gemm_logits<<<(B * T / 128) * (V / 128), 512, 0, stream>>>(
        outs_bf, outw_bf, out_b, log_probs, stats, B * T, V, H);
    lsesub_kernel<<<B * T, 256, 0, stream>>>(stats, log_probs);
}